// Round 1
// baseline (464.007 us; speedup 1.0000x reference)
//
#include <hip/hip_runtime.h>
#include <math.h>

// Problem constants
#define Bsz 1024
#define Dd  256
#define Hh  512
#define Aa  4
#define Kk  32          // 2*A*A
#define NOUT 8192       // D*K

// ---------------- masked GEMM: C[M,N] = act(A[M,Kd] @ (mask*W)[N,Kd]^T + bias) ---------
// MASK 0: m0  (row h in [0,512), col k in [0,256)):  (h%255) >= k
// MASK 1: mh  (row h, col k in [0,512)):             (h%255) >= (k%255)
// MASK 2: ml  (row r in [0,8192), col k in [0,512)): (r>>5)-1 >= (k%255)
#define BM 64
#define BN 64
#define BK 16
#define PAD 4

template<int MASK, int RELU>
__global__ __launch_bounds__(256) void gemm_masked(
    const float* __restrict__ A, const float* __restrict__ W,
    const float* __restrict__ bias, float* __restrict__ C,
    int M, int N, int Kd)
{
  __shared__ float As[BK][BM + PAD];
  __shared__ float Ws[BK][BN + PAD];
  const int bm = blockIdx.y, bn = blockIdx.x;
  const int tid = threadIdx.x;          // 0..255
  const int tx = tid & 15, ty = tid >> 4;
  const int row0 = bm * BM, col0 = bn * BN;
  float acc[4][4] = {};

  for (int kt = 0; kt < Kd; kt += BK) {
#pragma unroll
    for (int i = 0; i < 4; i++) {
      int l = tid + 256 * i;            // 0..1023 over the 64x16 tile
      int m = l >> 4, k = l & 15;       // k consecutive per lane -> coalesced
      As[k][m] = A[(size_t)(row0 + m) * Kd + kt + k];
      int gn = col0 + m, gk = kt + k;
      float w = W[(size_t)gn * Kd + gk];
      bool valid;
      if (MASK == 0)      valid = (gn % 255) >= gk;
      else if (MASK == 1) valid = (gn % 255) >= (gk % 255);
      else                valid = ((gn >> 5) - 1) >= (gk % 255);
      Ws[k][m] = valid ? w : 0.0f;
    }
    __syncthreads();
#pragma unroll
    for (int k = 0; k < BK; k++) {
      float4 a4 = *reinterpret_cast<const float4*>(&As[k][ty * 4]);
      float4 w4 = *reinterpret_cast<const float4*>(&Ws[k][tx * 4]);
      float a[4] = {a4.x, a4.y, a4.z, a4.w};
      float w[4] = {w4.x, w4.y, w4.z, w4.w};
#pragma unroll
      for (int i = 0; i < 4; i++)
#pragma unroll
        for (int j = 0; j < 4; j++)
          acc[i][j] = fmaf(a[i], w[j], acc[i][j]);
    }
    __syncthreads();
  }

#pragma unroll
  for (int i = 0; i < 4; i++) {
    int r = row0 + ty * 4 + i;
    float4 v;
    float* vp = reinterpret_cast<float*>(&v);
#pragma unroll
    for (int j = 0; j < 4; j++) {
      int c = col0 + tx * 4 + j;
      float t = acc[i][j] + bias[c];
      if (RELU) t = fmaxf(t, 0.0f);
      vp[j] = t;
    }
    *reinterpret_cast<float4*>(&C[(size_t)r * N + col0 + tx * 4]) = v;
  }
}

// ---------------- lpa = log_softmax(ulpa, axis=-1), shape (255,4) -----------------------
__global__ void lpa_kernel(const float* __restrict__ ulpa, float* __restrict__ lpa)
{
  int d = blockIdx.x * blockDim.x + threadIdx.x;
  if (d < Dd - 1) {
    float v0 = ulpa[d * 4 + 0], v1 = ulpa[d * 4 + 1];
    float v2 = ulpa[d * 4 + 2], v3 = ulpa[d * 4 + 3];
    float m = fmaxf(fmaxf(v0, v1), fmaxf(v2, v3));
    float s = __expf(v0 - m) + __expf(v1 - m) + __expf(v2 - m) + __expf(v3 - m);
    float l = m + __logf(s);
    lpa[d * 4 + 0] = v0 - l;
    lpa[d * 4 + 1] = v1 - l;
    lpa[d * 4 + 2] = v2 - l;
    lpa[d * 4 + 3] = v3 - l;
  }
}

// ---------------- sequential logsumexp chain over D, 4 lanes per batch row --------------
__global__ __launch_bounds__(256) void chain_kernel(
    const float* __restrict__ x, const float* __restrict__ theta,
    const float* __restrict__ lpa, float* __restrict__ logp, int B)
{
  int t = blockIdx.x * blockDim.x + threadIdx.x;
  int b = t >> 2, j = t & 3;
  if (b >= B) return;
  const float C0 = 0.91893853320467274178f;   // 0.5*log(2*pi)
  const float* th = theta + (size_t)b * NOUT;
  const float* xb = x + (size_t)b * Dd;

  // log N(x_d | mu(d,i,jj), std(d,i,jj))
  auto logpx = [&](int d, int i, int jj) -> float {
    float mu = th[d * 32 + i * 4 + jj];
    float s  = __expf(th[d * 32 + 16 + i * 4 + jj]) + 0.01f;
    float z  = (xb[d] - mu) * (1.0f / s);
    return -0.5f * z * z - __logf(s) - C0;
  };

  // first = joint[:,0,0,:]  -> carry_j = logpx(0,0,j) + lpa[0,j]
  float carry = logpx(0, 0, j) + lpa[j];

  for (int d = 1; d < Dd - 1; d++) {
    float ci0 = __shfl(carry, 0, 4);
    float ci1 = __shfl(carry, 1, 4);
    float ci2 = __shfl(carry, 2, 4);
    float ci3 = __shfl(carry, 3, 4);
    float v0 = ci0 + logpx(d, 0, j);
    float v1 = ci1 + logpx(d, 1, j);
    float v2 = ci2 + logpx(d, 2, j);
    float v3 = ci3 + logpx(d, 3, j);
    float m = fmaxf(fmaxf(v0, v1), fmaxf(v2, v3));
    float s = __expf(v0 - m) + __expf(v1 - m) + __expf(v2 - m) + __expf(v3 - m);
    carry = m + __logf(s) + lpa[d * 4 + j];
  }

  // last: log_p = lse_i(carry[i] + logpx(D-1, i, 0))
  float v = carry + logpx(Dd - 1, j, 0);
  float m = v;
  m = fmaxf(m, __shfl_xor(m, 1, 4));
  m = fmaxf(m, __shfl_xor(m, 2, 4));
  float e = __expf(v - m);
  e += __shfl_xor(e, 1, 4);
  e += __shfl_xor(e, 2, 4);
  if (j == 0) logp[b] = m + __logf(e);
}

extern "C" void kernel_launch(void* const* d_in, const int* in_sizes, int n_in,
                              void* d_out, int out_size, void* d_ws, size_t ws_size,
                              hipStream_t stream)
{
  const float* x    = (const float*)d_in[0];
  const float* W0   = (const float*)d_in[1];
  const float* b0   = (const float*)d_in[2];
  const float* W1   = (const float*)d_in[3];
  const float* b1   = (const float*)d_in[4];
  const float* W2   = (const float*)d_in[5];
  const float* b2   = (const float*)d_in[6];
  const float* Wout = (const float*)d_in[7];
  const float* bout = (const float*)d_in[8];
  const float* ulpa = (const float*)d_in[9];

  float* out   = (float*)d_out;
  float* logp  = out;               // (B,1,1) = 1024 floats
  float* theta = out + Bsz;         // (B,D,2,A,A) = 8388608 floats

  float* ws = (float*)d_ws;
  float* h0  = ws;                          // 1024*512
  float* h1  = h0 + (size_t)Bsz * Hh;       // 1024*512
  float* h2  = h1 + (size_t)Bsz * Hh;       // 1024*512
  float* lpa = h2 + (size_t)Bsz * Hh;       // 255*4

  dim3 blk(256);
  gemm_masked<0, 1><<<dim3(Hh / BN, Bsz / BM), blk, 0, stream>>>(x,  W0,   b0,   h0,    Bsz, Hh,   Dd);
  gemm_masked<1, 1><<<dim3(Hh / BN, Bsz / BM), blk, 0, stream>>>(h0, W1,   b1,   h1,    Bsz, Hh,   Hh);
  gemm_masked<1, 1><<<dim3(Hh / BN, Bsz / BM), blk, 0, stream>>>(h1, W2,   b2,   h2,    Bsz, Hh,   Hh);
  gemm_masked<2, 0><<<dim3(NOUT / BN, Bsz / BM), blk, 0, stream>>>(h2, Wout, bout, theta, Bsz, NOUT, Hh);
  lpa_kernel<<<1, 256, 0, stream>>>(ulpa, lpa);
  chain_kernel<<<(Bsz * 4 + 255) / 256, 256, 0, stream>>>(x, theta, lpa, logp, Bsz);
}

// Round 2
// 215.946 us; speedup vs baseline: 2.1487x; 2.1487x over previous
//
#include <hip/hip_runtime.h>
#include <math.h>

#define Bsz 1024
#define Dd  256
#define Hh  512
#define NOUT 8192       // D*K, K=32

typedef __attribute__((ext_vector_type(8))) short bf8_t;   // 8 bf16 (4 VGPRs)
typedef __attribute__((ext_vector_type(4))) float f4_t;    // 4 fp32

__device__ inline ushort f2b(float f) {
  union { float f; unsigned u; } c; c.f = f;
  unsigned r = c.u + 0x7fffu + ((c.u >> 16) & 1u);   // RNE
  return (ushort)(r >> 16);
}

// ---------------- bf16 MFMA GEMM: C[M,N] = act(A @ (mask*W)^T + bias) ------------------
// A fp32 [M,Kd], W fp32 [N,Kd]; mask applied by index during LDS staging.
// MASK 0: (n%255) >= k ; MASK 1: (n%255) >= (k%255) ; MASK 2: (n>>5)-1 >= (k%255)
#define LDK 40   // padded ushort stride (80 B): (5m+q)%8 hits all bank groups; 8B-aligned

template<int BM2, int BN2, int MASK, int RELU>
__global__ __launch_bounds__(256) void gemm_mfma(
    const float* __restrict__ A, const float* __restrict__ W,
    const float* __restrict__ bias, float* __restrict__ C,
    int M, int N, int Kd)
{
  constexpr int WM = BM2 / 2, WN = BN2 / 2;
  constexpr int MI = WM / 16, NI = WN / 16;
  __shared__ ushort As[BM2 * LDK];
  __shared__ ushort Bs[BN2 * LDK];
  const int tid  = threadIdx.x;
  const int lane = tid & 63, wave = tid >> 6;
  const int waveM = wave >> 1, waveN = wave & 1;
  const int row0 = blockIdx.y * BM2, col0 = blockIdx.x * BN2;
  const int fm = lane & 15, q = lane >> 4;

  f4_t acc[MI][NI];
#pragma unroll
  for (int i = 0; i < MI; i++)
#pragma unroll
    for (int j = 0; j < NI; j++) acc[i][j] = (f4_t){0.f, 0.f, 0.f, 0.f};

  const int sc = tid & 7;    // 4-float chunk within the 32-wide k-tile
  const int sr = tid >> 3;   // row 0..31

  for (int kt = 0; kt < Kd; kt += 32) {
    // ---- stage A (fp32 -> bf16) ----
#pragma unroll
    for (int p = 0; p < BM2 / 32; p++) {
      int r = sr + p * 32;
      float4 v = *(const float4*)&A[(size_t)(row0 + r) * Kd + kt + sc * 4];
      ushort4 u; u.x = f2b(v.x); u.y = f2b(v.y); u.z = f2b(v.z); u.w = f2b(v.w);
      *(ushort4*)&As[r * LDK + sc * 4] = u;
    }
    // ---- stage W (mask + fp32 -> bf16) ----
#pragma unroll
    for (int p = 0; p < BN2 / 32; p++) {
      int r = sr + p * 32;
      int gn = col0 + r;
      float4 v = *(const float4*)&W[(size_t)gn * Kd + kt + sc * 4];
      float vv[4] = {v.x, v.y, v.z, v.w};
      ushort4 u; ushort* up = (ushort*)&u;
      int nd = (MASK == 2) ? ((gn >> 5) - 1) : (gn % 255);
#pragma unroll
      for (int e = 0; e < 4; e++) {
        int gk = kt + sc * 4 + e;
        int kd = (MASK == 0) ? gk : (gk % 255);
        up[e] = (nd >= kd) ? f2b(vv[e]) : (ushort)0;
      }
      *(ushort4*)&Bs[r * LDK + sc * 4] = u;
    }
    __syncthreads();

    bf8_t af[MI], bfr[NI];
#pragma unroll
    for (int i = 0; i < MI; i++)
      af[i] = *(const bf8_t*)&As[(waveM * WM + i * 16 + fm) * LDK + q * 8];
#pragma unroll
    for (int j = 0; j < NI; j++)
      bfr[j] = *(const bf8_t*)&Bs[(waveN * WN + j * 16 + fm) * LDK + q * 8];
#pragma unroll
    for (int i = 0; i < MI; i++)
#pragma unroll
      for (int j = 0; j < NI; j++)
        acc[i][j] = __builtin_amdgcn_mfma_f32_16x16x32_bf16(af[i], bfr[j], acc[i][j], 0, 0, 0);
    __syncthreads();
  }

  // epilogue: D row = q*4 + reg, col = fm  [m89 C/D layout]
#pragma unroll
  for (int j = 0; j < NI; j++) {
    int col = col0 + waveN * WN + j * 16 + fm;
    float bv = bias[col];
#pragma unroll
    for (int i = 0; i < MI; i++) {
#pragma unroll
      for (int r = 0; r < 4; r++) {
        int row = row0 + waveM * WM + i * 16 + q * 4 + r;
        float t = acc[i][j][r] + bv;
        if (RELU) t = fmaxf(t, 0.0f);
        C[(size_t)row * N + col] = t;
      }
    }
  }
}

// ---------------- lpa = log_softmax(ulpa, axis=-1), shape (255,4) -----------------------
__global__ void lpa_kernel(const float* __restrict__ ulpa, float* __restrict__ lpa)
{
  int d = blockIdx.x * blockDim.x + threadIdx.x;
  if (d < Dd - 1) {
    float v0 = ulpa[d * 4 + 0], v1 = ulpa[d * 4 + 1];
    float v2 = ulpa[d * 4 + 2], v3 = ulpa[d * 4 + 3];
    float m = fmaxf(fmaxf(v0, v1), fmaxf(v2, v3));
    float s = __expf(v0 - m) + __expf(v1 - m) + __expf(v2 - m) + __expf(v3 - m);
    float l = m + __logf(s);
    lpa[d * 4 + 0] = v0 - l;
    lpa[d * 4 + 1] = v1 - l;
    lpa[d * 4 + 2] = v2 - l;
    lpa[d * 4 + 3] = v3 - l;
  }
}

// ---------------- chain: segmented scan over the 4x4 log-semiring ----------------------
// One block per batch row. 16 segments x 16 matrix entries = 256 threads.
// Segment s computes T_s = M_{d0} (x) M_{d0+1} (x) ... (entry (i,jj) per thread,
// composition T'(i,jj) = LSE_j(T(i,j)+M(j,jj)) via intra-16-group shuffles),
// then 4 threads fold carry through the 16 segment matrices.
__global__ __launch_bounds__(256) void chain2(
    const float* __restrict__ x, const float* __restrict__ theta,
    const float* __restrict__ lpa, float* __restrict__ logp)
{
  const int b = blockIdx.x;
  const int tid = threadIdx.x;
  const int seg = tid >> 4, e = tid & 15;
  const int i = e >> 2, jj = e & 3;
  const int base = (tid & 63) & ~15;            // wave-lane base of this 16-group
  const float C0 = 0.91893853320467274178f;     // 0.5*log(2*pi)
  const float* th = theta + (size_t)b * NOUT;
  const float* xb = x + (size_t)b * Dd;
  __shared__ float Ts[16][16];

  const int d0 = 1 + seg * 16;
  const int d1 = min(d0 + 16, Dd - 1);

  // step matrix entry (row=e>>2, col=e&3): M_d(i,jj) = logpx(d,i,jj) + lpa[d,jj]
  auto stepm = [&](int d) -> float {
    float mu = th[d * 32 + e];
    float ls = th[d * 32 + 16 + e];
    float s  = __expf(ls) + 0.01f;
    float z  = (xb[d] - mu) / s;
    return -0.5f * z * z - __logf(s) - C0 + lpa[d * 4 + jj];
  };

  float T = stepm(d0);
  for (int d = d0 + 1; d < d1; d++) {
    float m_ = stepm(d);
    float v0 = __shfl(T, base + i * 4 + 0) + __shfl(m_, base + 0 * 4 + jj);
    float v1 = __shfl(T, base + i * 4 + 1) + __shfl(m_, base + 1 * 4 + jj);
    float v2 = __shfl(T, base + i * 4 + 2) + __shfl(m_, base + 2 * 4 + jj);
    float v3 = __shfl(T, base + i * 4 + 3) + __shfl(m_, base + 3 * 4 + jj);
    float mx = fmaxf(fmaxf(v0, v1), fmaxf(v2, v3));
    float s  = __expf(v0 - mx) + __expf(v1 - mx) + __expf(v2 - mx) + __expf(v3 - mx);
    T = mx + __logf(s);
  }
  Ts[seg][e] = T;
  __syncthreads();

  if (tid < 4) {
    const int j = tid;
    // carry init at d=0: logpx(0,0,j) + lpa[0,j]
    float mu = th[j], ls = th[16 + j];
    float s = __expf(ls) + 0.01f;
    float z = (xb[0] - mu) / s;
    float carry = -0.5f * z * z - __logf(s) - C0 + lpa[j];
#pragma unroll 1
    for (int sg = 0; sg < 16; sg++) {
      float c0 = __shfl(carry, 0);
      float c1 = __shfl(carry, 1);
      float c2 = __shfl(carry, 2);
      float c3 = __shfl(carry, 3);
      float v0 = c0 + Ts[sg][0 * 4 + j];
      float v1 = c1 + Ts[sg][1 * 4 + j];
      float v2 = c2 + Ts[sg][2 * 4 + j];
      float v3 = c3 + Ts[sg][3 * 4 + j];
      float mx = fmaxf(fmaxf(v0, v1), fmaxf(v2, v3));
      float ss = __expf(v0 - mx) + __expf(v1 - mx) + __expf(v2 - mx) + __expf(v3 - mx);
      carry = mx + __logf(ss);
    }
    // last: log_p = LSE_i(carry_i + logpx(D-1, i, 0))
    float mu2 = th[255 * 32 + j * 4], ls2 = th[255 * 32 + 16 + j * 4];
    float s2 = __expf(ls2) + 0.01f;
    float z2 = (xb[255] - mu2) / s2;
    float v = carry - 0.5f * z2 * z2 - __logf(s2) - C0;
    float mx = fmaxf(v, __shfl_xor(v, 1));
    mx = fmaxf(mx, __shfl_xor(mx, 2));
    float ee = __expf(v - mx);
    ee += __shfl_xor(ee, 1);
    ee += __shfl_xor(ee, 2);
    if (j == 0) logp[b] = mx + __logf(ee);
  }
}

extern "C" void kernel_launch(void* const* d_in, const int* in_sizes, int n_in,
                              void* d_out, int out_size, void* d_ws, size_t ws_size,
                              hipStream_t stream)
{
  const float* x    = (const float*)d_in[0];
  const float* W0   = (const float*)d_in[1];
  const float* b0   = (const float*)d_in[2];
  const float* W1   = (const float*)d_in[3];
  const float* b1   = (const float*)d_in[4];
  const float* W2   = (const float*)d_in[5];
  const float* b2   = (const float*)d_in[6];
  const float* Wout = (const float*)d_in[7];
  const float* bout = (const float*)d_in[8];
  const float* ulpa = (const float*)d_in[9];

  float* out   = (float*)d_out;
  float* logp  = out;               // (B,1,1)
  float* theta = out + Bsz;         // (B,D,2,A,A)

  float* ws  = (float*)d_ws;
  float* h0  = ws;                          // 1024*512 fp32
  float* h1  = h0 + (size_t)Bsz * Hh;
  float* h2  = h1 + (size_t)Bsz * Hh;
  float* lpa = h2 + (size_t)Bsz * Hh;       // 255*4

  gemm_mfma<64, 64, 0, 1><<<dim3(Hh / 64, Bsz / 64), 256, 0, stream>>>(x,  W0, b0, h0, Bsz, Hh, Dd);
  gemm_mfma<64, 64, 1, 1><<<dim3(Hh / 64, Bsz / 64), 256, 0, stream>>>(h0, W1, b1, h1, Bsz, Hh, Hh);
  gemm_mfma<64, 64, 1, 1><<<dim3(Hh / 64, Bsz / 64), 256, 0, stream>>>(h1, W2, b2, h2, Bsz, Hh, Hh);
  gemm_mfma<128, 128, 2, 0><<<dim3(NOUT / 128, Bsz / 128), 256, 0, stream>>>(h2, Wout, bout, theta, Bsz, NOUT, Hh);
  lpa_kernel<<<1, 256, 0, stream>>>(ulpa, lpa);
  chain2<<<Bsz, 256, 0, stream>>>(x, theta, lpa, logp);
}

// Round 3
// 144.846 us; speedup vs baseline: 3.2035x; 1.4909x over previous
//
#include <hip/hip_runtime.h>
#include <math.h>

#define Bsz 1024
#define Dd  256
#define Hh  512
#define NOUT 8192       // D*K, K=32

typedef __attribute__((ext_vector_type(8))) short bf8_t;   // 8 bf16 (4 VGPRs)
typedef __attribute__((ext_vector_type(4))) float f4_t;    // 4 fp32

__device__ inline ushort f2b(float f) {
  union { float f; unsigned u; } c; c.f = f;
  unsigned r = c.u + 0x7fffu + ((c.u >> 16) & 1u);   // RNE
  return (ushort)(r >> 16);
}

__device__ inline void async16(const ushort* g, ushort* l) {
  __builtin_amdgcn_global_load_lds((const __attribute__((address_space(1))) void*)g,
                                   (__attribute__((address_space(3))) void*)l, 16, 0, 0);
}

__device__ inline int mod255(int v) {   // valid for v in [0, 765)
  if (v >= 510) return v - 510;
  if (v >= 255) return v - 255;
  return v;
}

// ---------- prep: fp32 -> bf16 (+mask) for x, W0, W1, W2, Wout -------------------------
// blocks: [0,128) x | [128,192) W0 | [192,320) W1 | [320,448) W2 | [448,2496) Wout
__global__ __launch_bounds__(256) void prep(
    const float* __restrict__ x,  const float* __restrict__ W0,
    const float* __restrict__ W1, const float* __restrict__ W2,
    const float* __restrict__ Wout,
    ushort* __restrict__ xb, ushort* __restrict__ w0b, ushort* __restrict__ w1b,
    ushort* __restrict__ w2b, ushort* __restrict__ woutb)
{
  const int blk = blockIdx.x, tid = threadIdx.x;
  const float* src; ushort* dst; int lb, mode;
  if (blk < 128)      { src = x;    dst = xb;    lb = blk;       mode = 0; }
  else if (blk < 192) { src = W0;   dst = w0b;   lb = blk - 128; mode = 1; }
  else if (blk < 320) { src = W1;   dst = w1b;   lb = blk - 192; mode = 2; }
  else if (blk < 448) { src = W2;   dst = w2b;   lb = blk - 320; mode = 2; }
  else                { src = Wout; dst = woutb; lb = blk - 448; mode = 3; }

  const int e = lb * 2048 + tid * 8;
  float4 v0 = *(const float4*)(src + e);
  float4 v1 = *(const float4*)(src + e + 4);
  float vv[8] = {v0.x, v0.y, v0.z, v0.w, v1.x, v1.y, v1.z, v1.w};
  ushort u[8];
  if (mode == 0) {
#pragma unroll
    for (int i = 0; i < 8; i++) u[i] = f2b(vv[i]);
  } else if (mode == 1) {            // Kd=256: (n%255) >= k
    int n = e >> 8, k0 = e & 255, nd = mod255(n);
#pragma unroll
    for (int i = 0; i < 8; i++) u[i] = (nd >= k0 + i) ? f2b(vv[i]) : (ushort)0;
  } else if (mode == 2) {            // Kd=512: (n%255) >= (k%255)
    int n = e >> 9, k0 = e & 511, nd = mod255(n);
#pragma unroll
    for (int i = 0; i < 8; i++) u[i] = (nd >= mod255(k0 + i)) ? f2b(vv[i]) : (ushort)0;
  } else {                           // Kd=512: (n>>5)-1 >= (k%255)
    int n = e >> 9, k0 = e & 511, nd = (n >> 5) - 1;
#pragma unroll
    for (int i = 0; i < 8; i++) u[i] = (nd >= mod255(k0 + i)) ? f2b(vv[i]) : (ushort)0;
  }
  *(ushort4*)(dst + e)     = *(ushort4*)&u[0];
  *(ushort4*)(dst + e + 4) = *(ushort4*)&u[4];
}

// ---------- bf16 MFMA GEMM with global_load_lds staging --------------------------------
// C[M,N] = act(A @ W^T + bias); A,W bf16 row-major [.,Kd] (W pre-masked).
// BK=64 (128B rows in LDS, no pad); XOR chunk swizzle: slot = (chunk + row) & 7.
template<int BM, int BN, int RELU, int OUTF32>
__global__ __launch_bounds__(256) void gemm_bf(
    const ushort* __restrict__ A, const ushort* __restrict__ W,
    const float* __restrict__ bias, float* __restrict__ Cf, ushort* __restrict__ Ch,
    int M, int N, int Kd)
{
  constexpr int WM = BM / 2, WN = BN / 2, MI = WM / 16, NI = WN / 16;
  __shared__ ushort As[BM * 64];
  __shared__ ushort Bs[BN * 64];
  const int tid = threadIdx.x, lane = tid & 63, wave = tid >> 6;
  const int waveM = wave >> 1, waveN = wave & 1;
  const int row0 = blockIdx.y * BM, col0 = blockIdx.x * BN;
  const int fm = lane & 15, qq = lane >> 4;
  const int srow = lane >> 3, qslot = lane & 7;

  f4_t acc[MI][NI];
#pragma unroll
  for (int i = 0; i < MI; i++)
#pragma unroll
    for (int j = 0; j < NI; j++) acc[i][j] = (f4_t){0.f, 0.f, 0.f, 0.f};

  for (int kt = 0; kt < Kd; kt += 64) {
    // stage A: each instr covers 8 rows x 8 chunks (64 lanes x 16B)
#pragma unroll
    for (int p = 0; p < BM / 32; p++) {
      int rb = p * 32 + wave * 8;
      int r = rb + srow;
      int q = (qslot - r) & 7;                  // logical chunk landing in slot qslot
      const ushort* g = A + (size_t)(row0 + r) * Kd + kt + q * 8;
      async16(g, &As[rb * 64]);
    }
#pragma unroll
    for (int p = 0; p < BN / 32; p++) {
      int rb = p * 32 + wave * 8;
      int r = rb + srow;
      int q = (qslot - r) & 7;
      const ushort* g = W + (size_t)(col0 + r) * Kd + kt + q * 8;
      async16(g, &Bs[rb * 64]);
    }
    __syncthreads();                            // drains vmcnt before barrier

#pragma unroll
    for (int t = 0; t < 2; t++) {
      bf8_t af[MI], bf[NI];
#pragma unroll
      for (int i = 0; i < MI; i++) {
        int r = waveM * WM + i * 16 + fm;
        int slot = ((t * 4 + qq) + r) & 7;
        af[i] = *(const bf8_t*)&As[r * 64 + slot * 8];
      }
#pragma unroll
      for (int j = 0; j < NI; j++) {
        int r = waveN * WN + j * 16 + fm;
        int slot = ((t * 4 + qq) + r) & 7;
        bf[j] = *(const bf8_t*)&Bs[r * 64 + slot * 8];
      }
#pragma unroll
      for (int i = 0; i < MI; i++)
#pragma unroll
        for (int j = 0; j < NI; j++)
          acc[i][j] = __builtin_amdgcn_mfma_f32_16x16x32_bf16(af[i], bf[j], acc[i][j], 0, 0, 0);
    }
    __syncthreads();
  }

  // epilogue: C/D layout row = qq*4 + r, col = fm
#pragma unroll
  for (int j = 0; j < NI; j++) {
    int col = col0 + waveN * WN + j * 16 + fm;
    float bv = bias[col];
#pragma unroll
    for (int i = 0; i < MI; i++) {
      int rbase = row0 + waveM * WM + i * 16 + qq * 4;
#pragma unroll
      for (int r = 0; r < 4; r++) {
        float t = acc[i][j][r] + bv;
        if (RELU) t = fmaxf(t, 0.0f);
        if (OUTF32) Cf[(size_t)(rbase + r) * N + col] = t;
        else        Ch[(size_t)(rbase + r) * N + col] = f2b(t);
      }
    }
  }
}

// ---------------- lpa = log_softmax(ulpa, axis=-1), shape (255,4) -----------------------
__global__ void lpa_kernel(const float* __restrict__ ulpa, float* __restrict__ lpa)
{
  int d = blockIdx.x * blockDim.x + threadIdx.x;
  if (d < Dd - 1) {
    float v0 = ulpa[d * 4 + 0], v1 = ulpa[d * 4 + 1];
    float v2 = ulpa[d * 4 + 2], v3 = ulpa[d * 4 + 3];
    float m = fmaxf(fmaxf(v0, v1), fmaxf(v2, v3));
    float s = __expf(v0 - m) + __expf(v1 - m) + __expf(v2 - m) + __expf(v3 - m);
    float l = m + __logf(s);
    lpa[d * 4 + 0] = v0 - l;
    lpa[d * 4 + 1] = v1 - l;
    lpa[d * 4 + 2] = v2 - l;
    lpa[d * 4 + 3] = v3 - l;
  }
}

// ---------------- chain: segmented scan over the 4x4 log-semiring ----------------------
__global__ __launch_bounds__(256) void chain2(
    const float* __restrict__ x, const float* __restrict__ theta,
    const float* __restrict__ lpa, float* __restrict__ logp)
{
  const int b = blockIdx.x;
  const int tid = threadIdx.x;
  const int seg = tid >> 4, e = tid & 15;
  const int i = e >> 2, jj = e & 3;
  const int base = (tid & 63) & ~15;
  const float C0 = 0.91893853320467274178f;     // 0.5*log(2*pi)
  const float* th = theta + (size_t)b * NOUT;
  const float* xb = x + (size_t)b * Dd;
  __shared__ float Ts[16][16];

  const int d0 = 1 + seg * 16;
  const int d1 = min(d0 + 16, Dd - 1);

  auto stepm = [&](int d) -> float {
    float mu = th[d * 32 + e];
    float ls = th[d * 32 + 16 + e];
    float s  = __expf(ls) + 0.01f;
    float z  = (xb[d] - mu) * __builtin_amdgcn_rcpf(s);
    return -0.5f * z * z - __logf(s) - C0 + lpa[d * 4 + jj];
  };

  float T = stepm(d0);
  for (int d = d0 + 1; d < d1; d++) {
    float m_ = stepm(d);
    float v0 = __shfl(T, base + i * 4 + 0) + __shfl(m_, base + 0 * 4 + jj);
    float v1 = __shfl(T, base + i * 4 + 1) + __shfl(m_, base + 1 * 4 + jj);
    float v2 = __shfl(T, base + i * 4 + 2) + __shfl(m_, base + 2 * 4 + jj);
    float v3 = __shfl(T, base + i * 4 + 3) + __shfl(m_, base + 3 * 4 + jj);
    float mx = fmaxf(fmaxf(v0, v1), fmaxf(v2, v3));
    float s  = __expf(v0 - mx) + __expf(v1 - mx) + __expf(v2 - mx) + __expf(v3 - mx);
    T = mx + __logf(s);
  }
  Ts[seg][e] = T;
  __syncthreads();

  if (tid < 4) {
    const int j = tid;
    float mu = th[j], ls = th[16 + j];
    float s = __expf(ls) + 0.01f;
    float z = (xb[0] - mu) * __builtin_amdgcn_rcpf(s);
    float carry = -0.5f * z * z - __logf(s) - C0 + lpa[j];
#pragma unroll 1
    for (int sg = 0; sg < 16; sg++) {
      float c0 = __shfl(carry, 0);
      float c1 = __shfl(carry, 1);
      float c2 = __shfl(carry, 2);
      float c3 = __shfl(carry, 3);
      float v0 = c0 + Ts[sg][0 * 4 + j];
      float v1 = c1 + Ts[sg][1 * 4 + j];
      float v2 = c2 + Ts[sg][2 * 4 + j];
      float v3 = c3 + Ts[sg][3 * 4 + j];
      float mx = fmaxf(fmaxf(v0, v1), fmaxf(v2, v3));
      float ss = __expf(v0 - mx) + __expf(v1 - mx) + __expf(v2 - mx) + __expf(v3 - mx);
      carry = mx + __logf(ss);
    }
    float mu2 = th[255 * 32 + j * 4], ls2 = th[255 * 32 + 16 + j * 4];
    float s2 = __expf(ls2) + 0.01f;
    float z2 = (xb[255] - mu2) * __builtin_amdgcn_rcpf(s2);
    float v = carry - 0.5f * z2 * z2 - __logf(s2) - C0;
    float mx = fmaxf(v, __shfl_xor(v, 1));
    mx = fmaxf(mx, __shfl_xor(mx, 2));
    float ee = __expf(v - mx);
    ee += __shfl_xor(ee, 1);
    ee += __shfl_xor(ee, 2);
    if (j == 0) logp[b] = mx + __logf(ee);
  }
}

extern "C" void kernel_launch(void* const* d_in, const int* in_sizes, int n_in,
                              void* d_out, int out_size, void* d_ws, size_t ws_size,
                              hipStream_t stream)
{
  const float* x    = (const float*)d_in[0];
  const float* W0   = (const float*)d_in[1];
  const float* b0   = (const float*)d_in[2];
  const float* W1   = (const float*)d_in[3];
  const float* b1   = (const float*)d_in[4];
  const float* W2   = (const float*)d_in[5];
  const float* b2   = (const float*)d_in[6];
  const float* Wout = (const float*)d_in[7];
  const float* bout = (const float*)d_in[8];
  const float* ulpa = (const float*)d_in[9];

  float* out   = (float*)d_out;
  float* logp  = out;               // (B,1,1)
  float* theta = out + Bsz;         // (B,D,2,A,A) fp32

  ushort* ws    = (ushort*)d_ws;
  ushort* xb    = ws;                       // 262144
  ushort* w0b   = xb + 262144;              // 131072
  ushort* w1b   = w0b + 131072;             // 262144
  ushort* w2b   = w1b + 262144;             // 262144
  ushort* woutb = w2b + 262144;             // 4194304
  ushort* h0    = woutb + 4194304;          // 524288
  ushort* h1    = h0 + 524288;              // 524288
  ushort* h2    = h0;                       // alias: h0 free after layer 2
  float*  lpa   = (float*)(h1 + 524288);    // 1020 floats

  prep<<<2496, 256, 0, stream>>>(x, W0, W1, W2, Wout, xb, w0b, w1b, w2b, woutb);
  lpa_kernel<<<1, 256, 0, stream>>>(ulpa, lpa);
  gemm_bf<64, 64, 1, 0><<<dim3(Hh / 64, Bsz / 64), 256, 0, stream>>>(xb, w0b, b0, nullptr, h0, Bsz, Hh, Dd);
  gemm_bf<64, 64, 1, 0><<<dim3(Hh / 64, Bsz / 64), 256, 0, stream>>>(h0, w1b, b1, nullptr, h1, Bsz, Hh, Hh);
  gemm_bf<64, 64, 1, 0><<<dim3(Hh / 64, Bsz / 64), 256, 0, stream>>>(h1, w2b, b2, nullptr, h2, Bsz, Hh, Hh);
  gemm_bf<128, 128, 0, 1><<<dim3(NOUT / 128, Bsz / 128), 256, 0, stream>>>(h2, woutb, bout, theta, nullptr, Bsz, NOUT, Hh);
  chain2<<<Bsz, 256, 0, stream>>>(x, theta, lpa, logp);
}